// Round 6
// baseline (116.342 us; speedup 1.0000x reference)
//
#include <hip/hip_runtime.h>

// CARAFE forward: N=8, C=128, H=64, W=64, k=5, G=1, s=2.
// out[n,c,2h+p,2w+q] = sum_{i,j} feat[n,c,h+i-2,w+j-2] * masks[n,i*5+j,2h+p,2w+q]
//
// Round 5 (resubmit — round-5 bench died on infra, kernel never measured):
// DS-pipe was the bottleneck (800 ds_read_b32/block ~= 31us/CU).
// Fix: interleave 4 channels in LDS minor dim -> one ds_read_b128 per tap
// serves 4 channels; wave owns a 4-channel group and ALL 4 (p,q) outputs
// (no p-duplication of reads). DS drops to 100 b128/block (~8us/CU).
// Masks: 25 taps x 4 (p,q) = 100 floats pinned in VGPRs via empty asm.

#define KK 5
#define PAD 2
#define CIN 128
#define HH 64
#define WW 64
#define HO 128
#define WO 128
#define NG 4                     // channel groups (= waves) per block
#define GC 4                     // channels per group, interleaved in LDS
#define CH_PER_BLOCK (NG * GC)   // 16
#define LCOLS 68                 // 2 halo | 64 data | 2 halo

__global__ __launch_bounds__(256, 2)
void carafe_fwd(const float* __restrict__ feat,
                const float* __restrict__ masks,
                float* __restrict__ out) {
    __shared__ float lds[NG][KK][LCOLS][GC];   // 21760 B

    const int tid  = threadIdx.x;
    const int lane = tid & 63;          // low-res w
    const int g    = tid >> 6;          // wave id = channel group
    const int h    = blockIdx.x;        // low-res h
    const int c0   = blockIdx.y * CH_PER_BLOCK;
    const int n    = blockIdx.z;

    // ---- all 4 (p,q) masks for 25 taps: 100 floats, pinned in VGPRs ----
    float2 m[KK * KK][2];
    const float* mb = masks + (size_t)n * (KK * KK) * HO * WO
                            + (size_t)(2 * h) * WO + 2 * lane;
    #pragma unroll
    for (int k = 0; k < KK * KK; ++k) {
        m[k][0] = *(const float2*)(mb + (size_t)k * HO * WO);
        m[k][1] = *(const float2*)(mb + (size_t)k * HO * WO + WO);
    }
    #pragma unroll
    for (int k = 0; k < KK * KK; ++k) {
        asm volatile("" : "+v"(m[k][0].x), "+v"(m[k][0].y),
                          "+v"(m[k][1].x), "+v"(m[k][1].y));
    }

    // ---- stage features, 4-channel interleaved; halo & OOB rows stay zero ----
    // item = (gg, r, c): lds[gg][r][c][0..3] = feat[c0+4gg+ci][h-2+r][c-2]
    const float* fb = feat + ((size_t)n * CIN + c0) * HH * WW;
    #pragma unroll
    for (int t = 0; t < 6; ++t) {
        int idx = t * 256 + tid;                 // 0..1535, 1360 live
        if (idx < NG * KK * LCOLS) {
            int gg  = idx / (KK * LCOLS);
            int rem = idx - gg * (KK * LCOLS);
            int r   = rem / LCOLS;
            int c   = rem - r * LCOLS;
            int rr  = h - PAD + r;
            int fc  = c - 2;
            float4 v = make_float4(0.f, 0.f, 0.f, 0.f);
            if ((unsigned)rr < (unsigned)HH && (unsigned)fc < (unsigned)WW) {
                const float* s = fb + ((size_t)(gg * GC) * HH + rr) * WW + fc;
                v.x = s[0 * HH * WW];
                v.y = s[1 * HH * WW];
                v.z = s[2 * HH * WW];
                v.w = s[3 * HH * WW];
            }
            *(float4*)&lds[gg][r][c][0] = v;
        }
    }
    __syncthreads();

    // ---- compute: 25 taps, each one ds_read_b128 (4 ch) + 16 fmac ----
    float2 acc[GC][2];
    #pragma unroll
    for (int ci = 0; ci < GC; ++ci) {
        acc[ci][0] = make_float2(0.f, 0.f);
        acc[ci][1] = make_float2(0.f, 0.f);
    }

    #pragma unroll
    for (int i = 0; i < KK; ++i) {
        #pragma unroll
        for (int j = 0; j < KK; ++j) {
            // feature col (lane + j - 2) lives at LDS col (lane + j)
            const float4 f4 = *(const float4*)&lds[g][i][lane + j][0];
            const float2 m0 = m[i * KK + j][0];
            const float2 m1 = m[i * KK + j][1];
            acc[0][0].x += f4.x * m0.x;  acc[0][0].y += f4.x * m0.y;
            acc[0][1].x += f4.x * m1.x;  acc[0][1].y += f4.x * m1.y;
            acc[1][0].x += f4.y * m0.x;  acc[1][0].y += f4.y * m0.y;
            acc[1][1].x += f4.y * m1.x;  acc[1][1].y += f4.y * m1.y;
            acc[2][0].x += f4.z * m0.x;  acc[2][0].y += f4.z * m0.y;
            acc[2][1].x += f4.z * m1.x;  acc[2][1].y += f4.z * m1.y;
            acc[3][0].x += f4.w * m0.x;  acc[3][0].y += f4.w * m0.y;
            acc[3][1].x += f4.w * m1.x;  acc[3][1].y += f4.w * m1.y;
        }
    }

    // ---- store: 4 ch x 2 rows, float2 (both q), coalesced ----
    float* ob = out + ((size_t)n * CIN + c0 + g * GC) * HO * WO
                    + (size_t)(2 * h) * WO + 2 * lane;
    #pragma unroll
    for (int ci = 0; ci < GC; ++ci) {
        *(float2*)(ob + (size_t)ci * HO * WO)      = acc[ci][0];
        *(float2*)(ob + (size_t)ci * HO * WO + WO) = acc[ci][1];
    }
}

extern "C" void kernel_launch(void* const* d_in, const int* in_sizes, int n_in,
                              void* d_out, int out_size, void* d_ws, size_t ws_size,
                              hipStream_t stream) {
    const float* feat  = (const float*)d_in[0];
    const float* masks = (const float*)d_in[1];
    float* out = (float*)d_out;

    dim3 grid(HH, CIN / CH_PER_BLOCK, 8);   // (h, c-group, n) = (64, 8, 8)
    dim3 block(256);
    carafe_fwd<<<grid, block, 0, stream>>>(feat, masks, out);
}

// Round 7
// 114.813 us; speedup vs baseline: 1.0133x; 1.0133x over previous
//
#include <hip/hip_runtime.h>

// CARAFE forward: N=8, C=128, H=64, W=64, k=5, G=1, s=2.
// out[n,c,2h+p,2w+q] = sum_{i,j} feat[n,c,h+i-2,w+j-2] * masks[n,i*5+j,2h+p,2w+q]
//
// Round 7: round 6 showed VGPR=64 with 116 forced-live floats -> compiler
// spilled the pinned masks (LLVM memory-bound perf-hint targets 8 waves/SIMD).
// Fix: (a) amdgpu_waves_per_eu(4,4) pins the occupancy target -> 128-VGPR
// budget; (b) p split across waves so resident masks = 50 floats (fits).
// Wave = (p, channel-half of 8); per tap: 2x ds_read_b128 (4ch each) + 16 fmac.

#define KK 5
#define PAD 2
#define CIN 128
#define HH 64
#define WW 64
#define HO 128
#define WO 128
#define NG 4                     // 4-channel groups in LDS
#define GC 4                     // channels interleaved in LDS minor dim
#define CH_PER_BLOCK (NG * GC)   // 16
#define LCOLS 68                 // 2 halo | 64 data | 2 halo

__global__ __launch_bounds__(256) __attribute__((amdgpu_waves_per_eu(4, 4)))
void carafe_fwd(const float* __restrict__ feat,
                const float* __restrict__ masks,
                float* __restrict__ out) {
    __shared__ float lds[NG][KK][LCOLS][GC];   // 21760 B

    const int tid  = threadIdx.x;
    const int lane = tid & 63;          // low-res w
    const int wid  = tid >> 6;          // 0..3
    const int p    = wid & 1;           // sub-pixel output row
    const int gsub = wid >> 1;          // channel half (8 channels)
    const int h    = blockIdx.x;        // low-res h
    const int c0   = blockIdx.y * CH_PER_BLOCK;
    const int n    = blockIdx.z;
    const int ho   = 2 * h + p;

    // ---- this wave's 25 mask float2 (q0,q1 at row ho): 50 floats, pinned ----
    float2 m[KK * KK];
    const float* mb = masks + (size_t)n * (KK * KK) * HO * WO
                            + (size_t)ho * WO + 2 * lane;
    #pragma unroll
    for (int k = 0; k < KK * KK; ++k) {
        m[k] = *(const float2*)(mb + (size_t)k * HO * WO);
    }
    #pragma unroll
    for (int k = 0; k < KK * KK; ++k) {
        asm volatile("" : "+v"(m[k].x), "+v"(m[k].y));   // no remat / re-load
    }

    // ---- stage features, 4-channel interleaved; halo & OOB rows zeroed ----
    const float* fb = feat + ((size_t)n * CIN + c0) * HH * WW;
    #pragma unroll
    for (int t = 0; t < 6; ++t) {
        int idx = t * 256 + tid;                 // 0..1535, 1360 live
        if (idx < NG * KK * LCOLS) {
            int gg  = idx / (KK * LCOLS);
            int rem = idx - gg * (KK * LCOLS);
            int r   = rem / LCOLS;
            int c   = rem - r * LCOLS;
            int rr  = h - PAD + r;
            int fc  = c - 2;
            float4 v = make_float4(0.f, 0.f, 0.f, 0.f);
            if ((unsigned)rr < (unsigned)HH && (unsigned)fc < (unsigned)WW) {
                const float* s = fb + ((size_t)(gg * GC) * HH + rr) * WW + fc;
                v.x = s[0 * HH * WW];
                v.y = s[1 * HH * WW];
                v.z = s[2 * HH * WW];
                v.w = s[3 * HH * WW];
            }
            *(float4*)&lds[gg][r][c][0] = v;
        }
    }
    __syncthreads();

    // ---- compute: 25 taps x (2 ds_read_b128 + 16 fmac), branch-free ----
    float2 acc[2 * GC];
    #pragma unroll
    for (int ci = 0; ci < 2 * GC; ++ci) acc[ci] = make_float2(0.f, 0.f);

    #pragma unroll
    for (int i = 0; i < KK; ++i) {
        #pragma unroll
        for (int j = 0; j < KK; ++j) {
            // feature col (lane + j - 2) lives at LDS col (lane + j)
            const float4 fa = *(const float4*)&lds[2 * gsub + 0][i][lane + j][0];
            const float4 fb4 = *(const float4*)&lds[2 * gsub + 1][i][lane + j][0];
            const float2 mk = m[i * KK + j];
            acc[0].x += fa.x * mk.x;   acc[0].y += fa.x * mk.y;
            acc[1].x += fa.y * mk.x;   acc[1].y += fa.y * mk.y;
            acc[2].x += fa.z * mk.x;   acc[2].y += fa.z * mk.y;
            acc[3].x += fa.w * mk.x;   acc[3].y += fa.w * mk.y;
            acc[4].x += fb4.x * mk.x;  acc[4].y += fb4.x * mk.y;
            acc[5].x += fb4.y * mk.x;  acc[5].y += fb4.y * mk.y;
            acc[6].x += fb4.z * mk.x;  acc[6].y += fb4.z * mk.y;
            acc[7].x += fb4.w * mk.x;  acc[7].y += fb4.w * mk.y;
        }
    }

    // ---- store: 8 channels x float2 (both q) at row ho, coalesced ----
    float* ob = out + ((size_t)n * CIN + c0 + gsub * 2 * GC) * HO * WO
                    + (size_t)ho * WO + 2 * lane;
    #pragma unroll
    for (int ci = 0; ci < 2 * GC; ++ci) {
        *(float2*)(ob + (size_t)ci * HO * WO) = acc[ci];
    }
}

extern "C" void kernel_launch(void* const* d_in, const int* in_sizes, int n_in,
                              void* d_out, int out_size, void* d_ws, size_t ws_size,
                              hipStream_t stream) {
    const float* feat  = (const float*)d_in[0];
    const float* masks = (const float*)d_in[1];
    float* out = (float*)d_out;

    dim3 grid(HH, CIN / CH_PER_BLOCK, 8);   // (h, c-group, n) = (64, 8, 8)
    dim3 block(256);
    carafe_fwd<<<grid, block, 0, stream>>>(feat, masks, out);
}